// Round 2
// baseline (16989.395 us; speedup 1.0000x reference)
//
#include <hip/hip_runtime.h>
#include <stdint.h>

#define NEG_INF -100000000.0f

typedef unsigned short u16;
typedef __attribute__((ext_vector_type(8))) short v8s;
typedef __attribute__((ext_vector_type(4))) short v4s;
typedef __attribute__((ext_vector_type(4))) float v4f;

__device__ __forceinline__ float bf2f(u16 h){ return __uint_as_float(((unsigned)h)<<16); }
__device__ __forceinline__ u16 f2bf(float f){
  unsigned u = __float_as_uint(f);
  u = u + 0x7fffu + ((u>>16)&1u);
  return (u16)(u>>16);
}
__device__ __forceinline__ float sigm(float x){ return 1.0f/(1.0f+__expf(-x)); }
__device__ __forceinline__ float ftanh(float x){
  x = fminf(15.0f, fmaxf(-15.0f, x));
  float e = __expf(2.0f*x);
  return (e-1.0f)/(e+1.0f);
}

// f32 -> bf16 bulk convert (inputs live as f32 on device; compute uses bf16 arena)
__global__ void cvt_f32_bf16(const float* __restrict__ s, u16* __restrict__ d, int n){
  int i = blockIdx.x*256 + threadIdx.x;
  if (i < n) d[i] = f2bf(s[i]);
}

// ---------------------------------------------------------------------------
// Generic bf16 GEMM: C[M][N] = A[M][K] @ B[N][K]^T (+bias1+bias2)(+tanh)(+C)
// A row stride = lda elements; C row stride = ldc elements.
// GF_REMAP32: A row r -> (r>>4)*512 + t0 + (r&15)   (chunked-xg gather, C=16)
// ---------------------------------------------------------------------------
#define GF_OUTBF16 1
#define GF_TANH    2
#define GF_ACCUM   4
#define GF_REMAP32 8

__global__ __launch_bounds__(256) void gemm_bf16(
    const u16* __restrict__ A, long long lda,
    const u16* __restrict__ B,
    const u16* __restrict__ bias1, const u16* __restrict__ bias2,
    void* __restrict__ Cout, long long ldc,
    int M, int Nn, int K, int flags, int t0)
{
  __shared__ u16 As[8192];  // 128 rows x 128 bytes (swizzled)
  __shared__ u16 Bs[8192];
  int tid = threadIdx.x;
  int lane = tid & 63, w = tid >> 6;
  int wm = w >> 1, wn = w & 1;
  int bm = blockIdx.x * 128, bn = blockIdx.y * 128;

  v4f acc[4][4];
#pragma unroll
  for (int i=0;i<4;++i)
#pragma unroll
    for (int j=0;j<4;++j) acc[i][j] = (v4f){0.f,0.f,0.f,0.f};

#pragma unroll 1
  for (int ko = 0; ko < K; ko += 64) {
    __syncthreads();
#pragma unroll
    for (int it = 0; it < 8; ++it) {
      int c = tid + 256*it;        // 0..2047 chunks of 16B
      int half = c >> 10;          // 0=A 1=B
      int cc = c & 1023;
      int r = cc >> 3;             // 0..127
      int kcb = cc & 7;
      const u16* src;
      if (half == 0) {
        int row = min(bm + r, M-1);
        long long arow = row;
        if (flags & GF_REMAP32) arow = (long long)(row>>4)*512 + t0 + (row&15);
        src = A + (size_t)arow*(size_t)lda + ko + (kcb<<3);
      } else {
        int row = min(bn + r, Nn-1);
        src = B + (size_t)row*(size_t)K + ko + (kcb<<3);
      }
      v8s v = *(const v8s*)src;
      char* base = (char*)(half ? Bs : As);
      *(v8s*)(base + (r<<7) + ((kcb<<4) ^ ((r&7)<<4))) = v;
    }
    __syncthreads();
#pragma unroll
    for (int ks = 0; ks < 2; ++ks) {
      v8s af[4], bfr[4];
#pragma unroll
      for (int mt=0; mt<4; ++mt) {
        int r = wm*64 + mt*16 + (lane & 15);
        int kb = (ks<<6) + ((lane>>4)<<4);
        af[mt] = *(const v8s*)((const char*)As + (r<<7) + (kb ^ ((r&7)<<4)));
      }
#pragma unroll
      for (int nt=0; nt<4; ++nt) {
        int r = wn*64 + nt*16 + (lane & 15);
        int kb = (ks<<6) + ((lane>>4)<<4);
        bfr[nt] = *(const v8s*)((const char*)Bs + (r<<7) + (kb ^ ((r&7)<<4)));
      }
#pragma unroll
      for (int mt=0; mt<4; ++mt)
#pragma unroll
        for (int nt=0; nt<4; ++nt)
          acc[mt][nt] = __builtin_amdgcn_mfma_f32_16x16x32_bf16(af[mt], bfr[nt], acc[mt][nt], 0,0,0);
    }
  }

#pragma unroll
  for (int mt=0; mt<4; ++mt) {
#pragma unroll
    for (int nt=0; nt<4; ++nt) {
      int col = bn + wn*64 + nt*16 + (lane&15);
      if (col >= Nn) continue;
      float b = 0.f;
      if (bias1) b += bf2f(bias1[col]);
      if (bias2) b += bf2f(bias2[col]);
#pragma unroll
      for (int r=0; r<4; ++r) {
        int row = bm + wm*64 + mt*16 + ((lane>>4)<<2) + r;
        if (row >= M) continue;
        float v = acc[mt][nt][r] + b;
        if (flags & GF_ACCUM) v += ((float*)Cout)[(size_t)row*(size_t)ldc + col];
        if (flags & GF_TANH) v = ftanh(v);
        if (flags & GF_OUTBF16) ((u16*)Cout)[(size_t)row*(size_t)ldc + col] = f2bf(v);
        else                    ((float*)Cout)[(size_t)row*(size_t)ldc + col] = v;
      }
    }
  }
}

// ---------------------------------------------------------------------------
// One LSTM time-step for both directions.
// grid = 32 blocks: blockIdx>>4 = dir (0 fwd, 1 bwd), &15 = unit-group (32 units).
// 4 waves: wave w computes gate w (i,f,g,o) for its 32 units, all 64 batches.
// KX=128: layer0, embedding gather fused into LDS staging.
// USE_XG: layer1, reads chunked precomputed input projections xgc (C=16).
// ---------------------------------------------------------------------------
template<int KX, bool USE_XG>
__global__ __launch_bounds__(256) void lstm_step(
    const u16* __restrict__ xsrc,      // l0: embed_W (bf16 arena)
    const int* __restrict__ Xidx,      // l0 only
    const u16* __restrict__ Wih_f, const u16* __restrict__ Wih_b,
    const u16* __restrict__ Whh_f, const u16* __restrict__ Whh_b,
    const u16* __restrict__ bih_f, const u16* __restrict__ bhh_f,
    const u16* __restrict__ bih_b, const u16* __restrict__ bhh_b,
    const u16* __restrict__ xgc,       // [2][64*16][2048] chunked xg (USE_XG)
    u16* __restrict__ hbuf,            // [64][512][1024] layer output (+h_prev src)
    float* __restrict__ cbuf,          // [2][64][512]
    int step)
{
  __shared__ u16 stage[8192];          // 64 rows x 256B
  __shared__ float glds[8192];         // 4 gates x 64 n x 32 u

  int tid = threadIdx.x, lane = tid & 63, w = tid >> 6;
  int dir = blockIdx.x >> 4, ug = blockIdx.x & 15;
  int t     = dir ? (511 - step) : step;
  int tprev = dir ? (t + 1) : (t - 1);
  bool first = (step == 0);
  const u16* Wih = dir ? Wih_b : Wih_f;
  const u16* Whh = dir ? Whh_b : Whh_f;

  v4f acc[4][2];
#pragma unroll
  for (int i=0;i<4;++i){ acc[i][0]=(v4f){0,0,0,0}; acc[i][1]=(v4f){0,0,0,0}; }

  // ---- x-projection windows (layer0 only; layer1 uses xgc) ----
  if constexpr (!USE_XG) {
#pragma unroll 1
    for (int wx = 0; wx < KX/128; ++wx) {
      __syncthreads();
#pragma unroll
      for (int it=0; it<4; ++it) {
        int c = tid + 256*it;          // 0..1023
        int r = c >> 4, kcb = c & 15;
        int xrow = Xidx[r*512 + t];
        const char* src = (const char*)xsrc + ((size_t)xrow<<8) + (kcb<<4);
        v8s v = *(const v8s*)src;
        *(v8s*)((char*)stage + (r<<8) + ((kcb<<4) ^ ((r&7)<<4))) = v;
      }
      __syncthreads();
#pragma unroll
      for (int ks=0; ks<4; ++ks) {
        v8s af[4];
#pragma unroll
        for (int mt=0; mt<4; ++mt) {
          int r = mt*16 + (lane&15);
          int kb = (ks<<6) + ((lane>>4)<<4);
          af[mt] = *(const v8s*)((const char*)stage + (r<<8) + (kb ^ ((r&7)<<4)));
        }
#pragma unroll
        for (int nt=0; nt<2; ++nt) {
          int j = w*512 + ug*32 + nt*16 + (lane&15);
          int kg = (wx<<7) + (ks<<5) + ((lane>>4)<<3);
          v8s bfr = *(const v8s*)(Wih + (size_t)j*KX + kg);
#pragma unroll
          for (int mt=0; mt<4; ++mt)
            acc[mt][nt] = __builtin_amdgcn_mfma_f32_16x16x32_bf16(af[mt], bfr, acc[mt][nt], 0,0,0);
        }
      }
    }
  }

  // ---- recurrent (h_prev @ Whh^T) windows ----
  if (!first) {
#pragma unroll 1
    for (int wh = 0; wh < 4; ++wh) {
      __syncthreads();
#pragma unroll
      for (int it=0; it<4; ++it) {
        int c = tid + 256*it;
        int r = c >> 4, kcb = c & 15;
        const char* src = (const char*)hbuf
            + (((size_t)(r*512 + tprev))<<11) + ((size_t)dir<<10) + (wh<<8) + (kcb<<4);
        v8s v = *(const v8s*)src;
        *(v8s*)((char*)stage + (r<<8) + ((kcb<<4) ^ ((r&7)<<4))) = v;
      }
      __syncthreads();
#pragma unroll
      for (int ks=0; ks<4; ++ks) {
        v8s af[4];
#pragma unroll
        for (int mt=0; mt<4; ++mt) {
          int r = mt*16 + (lane&15);
          int kb = (ks<<6) + ((lane>>4)<<4);
          af[mt] = *(const v8s*)((const char*)stage + (r<<8) + (kb ^ ((r&7)<<4)));
        }
#pragma unroll
        for (int nt=0; nt<2; ++nt) {
          int j = w*512 + ug*32 + nt*16 + (lane&15);
          int kg = (wh<<7) + (ks<<5) + ((lane>>4)<<3);
          v8s bfr = *(const v8s*)(Whh + (size_t)j*512 + kg);
#pragma unroll
          for (int mt=0; mt<4; ++mt)
            acc[mt][nt] = __builtin_amdgcn_mfma_f32_16x16x32_bf16(af[mt], bfr, acc[mt][nt], 0,0,0);
        }
      }
    }
  }

  // ---- exchange gates across waves ----
#pragma unroll
  for (int mt=0; mt<4; ++mt)
#pragma unroll
    for (int nt=0; nt<2; ++nt)
#pragma unroll
      for (int r4=0; r4<4; ++r4) {
        int n = mt*16 + ((lane>>4)<<2) + r4;
        int u = nt*16 + (lane&15);
        glds[w*2048 + n*32 + u] = acc[mt][nt][r4];
      }
  __syncthreads();

  // ---- pointwise cell update ----
  const u16* bih = dir ? bih_b : bih_f;
  const u16* bhh = dir ? bhh_b : bhh_f;
#pragma unroll
  for (int it=0; it<8; ++it) {
    int p = tid + 256*it;              // 0..2047
    int n = p >> 5, u = p & 31;
    int uj = ug*32 + u;
    float g[4];
#pragma unroll
    for (int q=0; q<4; ++q) {
      int j = q*512 + uj;
      float add;
      if (USE_XG) add = bf2f(xgc[((size_t)((dir<<10) + (n<<4) + (t&15)))*2048 + j]);
      else        add = bf2f(bih[j]) + bf2f(bhh[j]);
      g[q] = glds[q*2048 + n*32 + u] + add;
    }
    size_t cidx = (size_t)dir*32768 + (size_t)n*512 + uj;
    float cp = first ? 0.f : cbuf[cidx];
    float cn = sigm(g[1])*cp + sigm(g[0])*ftanh(g[2]);
    float h  = sigm(g[3])*ftanh(cn);
    cbuf[cidx] = cn;
    hbuf[((size_t)(n*512 + t))*1024 + dir*512 + uj] = f2bf(h);
  }
}

// ---------------------------------------------------------------------------
// Fused attention step: per-batch block computes e -> masked softmax -> context
// ---------------------------------------------------------------------------
__global__ __launch_bounds__(256) void attn_step(
    const float* __restrict__ qbuf, const u16* __restrict__ Uah,
    const u16* __restrict__ hid, const int* __restrict__ seq_len,
    const u16* __restrict__ vaW, const u16* __restrict__ vab,
    u16* __restrict__ catb)
{
  int n = blockIdx.x, tid = threadIdx.x;
  __shared__ float qs[1024];
  __shared__ float vas[1024];
  __shared__ float es[512];
  __shared__ float red[8];
  for (int d=tid; d<1024; d+=256){ qs[d]=qbuf[n*1024+d]; vas[d]=bf2f(vaW[d]); }
  __syncthreads();
  int sl = seq_len[n];
  float vb = bf2f(vab[0]);
  for (int l=tid; l<512; l+=256) {
    const u16* up = Uah + ((size_t)n*512 + l)*1024;
    float a = 0.f;
    for (int d=0; d<1024; d+=8) {
      v8s uv = *(const v8s*)(up + d);
#pragma unroll
      for (int e=0;e<8;++e)
        a = fmaf(ftanh(bf2f((u16)uv[e]) + qs[d+e]), vas[d+e], a);
    }
    float ev = a + vb;
    if (l >= sl) ev += NEG_INF;
    es[l] = ev;
  }
  __syncthreads();
  float m = -3.4e38f;
  for (int l=tid; l<512; l+=256) m = fmaxf(m, es[l]);
#pragma unroll
  for (int off=1; off<64; off<<=1) m = fmaxf(m, __shfl_xor(m, off));
  if ((tid&63)==0) red[tid>>6] = m;
  __syncthreads();
  m = fmaxf(fmaxf(red[0],red[1]), fmaxf(red[2],red[3]));
  float s = 0.f;
  for (int l=tid; l<512; l+=256){ float p = __expf(es[l]-m); es[l]=p; s+=p; }
#pragma unroll
  for (int off=1; off<64; off<<=1) s += __shfl_xor(s, off);
  if ((tid&63)==0) red[4+(tid>>6)] = s;
  __syncthreads();
  float inv = 1.f/(red[4]+red[5]+red[6]+red[7]);
  // context: 4 consecutive d per thread
  int d0 = tid*4;
  float c0=0,c1=0,c2=0,c3=0;
  for (int l=0; l<512; ++l) {
    float a = es[l];
    const u16* hp = hid + ((size_t)n*512 + l)*1024 + d0;
    v4s hv = *(const v4s*)hp;
    c0 = fmaf(a, bf2f((u16)hv[0]), c0);
    c1 = fmaf(a, bf2f((u16)hv[1]), c1);
    c2 = fmaf(a, bf2f((u16)hv[2]), c2);
    c3 = fmaf(a, bf2f((u16)hv[3]), c3);
  }
  catb[n*2048 + d0 + 0] = f2bf(c0*inv);
  catb[n*2048 + d0 + 1] = f2bf(c1*inv);
  catb[n*2048 + d0 + 2] = f2bf(c2*inv);
  catb[n*2048 + d0 + 3] = f2bf(c3*inv);
}

// decoder pointwise: c = sig(i)*tanh(g); s = sig(o)*tanh(c)
__global__ void dec_pw(const float* __restrict__ g, u16* __restrict__ scat,
                       u16* __restrict__ catb, int it)
{
  int idx = blockIdx.x*256 + threadIdx.x;      // 65536
  int n = idx >> 10, d = idx & 1023;
  float gi = g[(size_t)n*4096 + d];
  float gg = g[(size_t)n*4096 + 2048 + d];
  float go = g[(size_t)n*4096 + 3072 + d];
  float c = sigm(gi)*ftanh(gg);
  float s = sigm(go)*ftanh(c);
  u16 hb = f2bf(s);
  scat[((size_t)n*11 + it)*1024 + d] = hb;
  catb[n*2048 + 1024 + d] = hb;
}

__global__ void fill_sentinel(float* out, int nel){
  int i = blockIdx.x*256 + threadIdx.x;
  if (i < nel) out[i] = 12345.0f;
}

// ---------------------------------------------------------------------------
extern "C" void kernel_launch(void* const* d_in, const int* in_sizes, int n_in,
                              void* d_out, int out_size, void* d_ws, size_t ws_size,
                              hipStream_t stream)
{
  const int* X      = (const int*)d_in[0];
  const int* seqlen = (const int*)d_in[1];
  float* out = (float*)d_out;
  char* ws = (char*)d_ws;

  // ---- bf16 parameter arena: convert all float inputs (f32 on device) ----
  // segs: {input idx, element count}
  struct Seg { int idx; int n; };
  static const Seg segs[31] = {
    {2, 4096000},
    {3, 262144},{4,1048576},{5,2048},{6,2048},
    {7, 262144},{8,1048576},{9,2048},{10,2048},
    {11,2097152},{12,1048576},{13,2048},{14,2048},
    {15,2097152},{16,1048576},{17,2048},{18,2048},
    {19,1048576},{20,1024},
    {21,1048576},{22,1024},
    {23,1048576},{24,1024},
    {25,1024},{26,1},
    {27,4194304},{28,4194304},{29,4096},{30,4096},
    {31,10240000},{32,10000},
  };
  const u16* bp[33];  // bf16 pointer per original input index
  size_t aoff = 0;    // elements
  for (int i = 0; i < 31; ++i) {
    bp[segs[i].idx] = (const u16*)(ws) + aoff;
    aoff += (size_t)((segs[i].n + 7) & ~7);
  }
  size_t arena_bytes = ((aoff*2 + 255) & ~(size_t)255);

  // workspace layout (bytes)
  const size_t H0_OFF   = arena_bytes;                 // 64MB; Uah aliases later
  const size_t HID_OFF  = H0_OFF   + 67108864;
  const size_t XGC_OFF  = HID_OFF  + 67108864;         // [2][1024][2048] bf16 = 8MB
  const size_t CBUF_OFF = XGC_OFF  + 8388608;
  const size_t CATB_OFF = CBUF_OFF + 262144;
  const size_t QBUF_OFF = CATB_OFF + 262144;
  const size_t GDEC_OFF = QBUF_OFF + 262144;
  const size_t SCAT_OFF = GDEC_OFF + 1048576;
  const size_t NEED     = SCAT_OFF + 1441792;

  if (ws_size < NEED) {  // distinctive failure signal (absmax ~12345)
    fill_sentinel<<<(out_size+255)/256, 256, 0, stream>>>(out, out_size);
    return;
  }

  u16*   h0   = (u16*)(ws + H0_OFF);
  u16*   Uah  = (u16*)(ws + H0_OFF);   // alias: h0 dead after encoder
  u16*   hid  = (u16*)(ws + HID_OFF);
  u16*   xgc  = (u16*)(ws + XGC_OFF);
  float* cbuf = (float*)(ws + CBUF_OFF);
  u16*   catb = (u16*)(ws + CATB_OFF);
  float* qbuf = (float*)(ws + QBUF_OFF);
  float* gdec = (float*)(ws + GDEC_OFF);
  u16*   scat = (u16*)(ws + SCAT_OFF);

  for (int i = 0; i < 31; ++i) {
    int n = segs[i].n;
    cvt_f32_bf16<<<(n+255)/256, 256, 0, stream>>>(
        (const float*)d_in[segs[i].idx], (u16*)bp[segs[i].idx], n);
  }

  // ---- encoder layer 0 (embedding gather fused into staging) ----
  for (int s = 0; s < 512; ++s)
    lstm_step<128,false><<<32, 256, 0, stream>>>(
        bp[2], X, bp[3], bp[7], bp[4], bp[8],
        bp[5], bp[6], bp[9], bp[10],
        nullptr, h0, cbuf, s);

  // ---- encoder layer 1: chunked xg (C=16) interleaved with scan ----
  for (int c = 0; c < 32; ++c) {
    int t0f = c*16, t0b = 496 - c*16;
    gemm_bf16<<<dim3(8,16), 256, 0, stream>>>(h0, 1024, bp[11], bp[13], bp[14],
        xgc, 2048, 1024, 2048, 1024, GF_OUTBF16|GF_REMAP32, t0f);
    gemm_bf16<<<dim3(8,16), 256, 0, stream>>>(h0, 1024, bp[15], bp[17], bp[18],
        xgc + (size_t)1024*2048, 2048, 1024, 2048, 1024, GF_OUTBF16|GF_REMAP32, t0b);
    for (int k = 0; k < 16; ++k)
      lstm_step<0,true><<<32, 256, 0, stream>>>(
          nullptr, nullptr, bp[11], bp[15], bp[12], bp[16],
          bp[13], bp[14], bp[17], bp[18],
          xgc, hid, cbuf, c*16 + k);
  }

  // ---- attention precompute ----
  gemm_bf16<<<dim3(256,8), 256, 0, stream>>>(hid, 1024, bp[23], bp[24], nullptr,
      Uah, 1024, 32768, 1024, 1024, GF_OUTBF16, 0);
  // s0 = tanh(hid[:,0,:] @ Ws^T + Ws_b) -> catb s-half
  gemm_bf16<<<dim3(1,8), 256, 0, stream>>>(hid, 524288, bp[19], bp[20], nullptr,
      catb + 1024, 2048, 64, 1024, 1024, GF_OUTBF16 | GF_TANH, 0);

  // ---- 11 decoder steps ----
  for (int it = 0; it < 11; ++it) {
    gemm_bf16<<<dim3(1,8), 256, 0, stream>>>(catb + 1024, 2048, bp[21], bp[22], nullptr,
        qbuf, 1024, 64, 1024, 1024, 0, 0);
    attn_step<<<64, 256, 0, stream>>>(qbuf, Uah, hid, seqlen, bp[25], bp[26], catb);
    gemm_bf16<<<dim3(1,32), 256, 0, stream>>>(catb, 2048, bp[27], bp[29], bp[30],
        gdec, 4096, 64, 4096, 1024, 0, 0);
    gemm_bf16<<<dim3(1,32), 256, 0, stream>>>(catb + 1024, 2048, bp[28], nullptr, nullptr,
        gdec, 4096, 64, 4096, 1024, GF_ACCUM, 0);
    dec_pw<<<256, 256, 0, stream>>>(gdec, scat, catb, it);
  }

  // ---- classifier (f32 output) ----
  gemm_bf16<<<dim3(6,79), 256, 0, stream>>>(scat, 1024, bp[31], bp[32], nullptr,
      out, 10000, 704, 10000, 1024, 0, 0);
}